// Round 13
// baseline (195.222 us; speedup 1.0000x reference)
//
#include <hip/hip_runtime.h>
#include <hip/hip_fp16.h>

// GCN 2-layer: N=50000 nodes, E=800000 edges, 128 -> 128(relu) -> 64
// R13: degree-balanced fused blocks. bin_build rank-sorts each bin's 128
// nodes by degree (O(128^2) LDS counting-rank, ~free) -> perm[]. The fused
// agg+gemm kernel's 16-node blocks take rank-consecutive nodes of one bin
// group, so all 16 waves have ~equal degree and the pre-MFMA barrier no
// longer pays max-of-16-Poisson straggler time (R12's ~12us hidden cost).
// Evidence log: R2 MLP depth win; R4/R9 sliced layouts dead; flat gather
// 86.6MB compulsory; R11 sentinel pad win; R12 fusion neutral (straggler).

#define N_NODES 50000
#define N_EDGES 800000
#define BINW    128
#define NBIN    391                    // ceil(50000/128); bin 390 has 80 nodes
#define CAP     2560                   // mean bin load 2046, ~11 sigma margin
#define CAP2    6656                   // padded: up to 2560 + 128*31
#define B_CHUNK 2048
#define NB_SCAT ((N_EDGES + B_CHUNK - 1) / B_CHUNK)   // 391

typedef __bf16 bf16x8 __attribute__((ext_vector_type(8)));
typedef float  f32x4  __attribute__((ext_vector_type(4)));

// ---------------- prep: W-frags, zero gcur, zero sentinel rows ----------------
template<int N>
__device__ inline void wprep_body(const float* __restrict__ W,
                                  __bf16* __restrict__ hi, __bf16* __restrict__ lo,
                                  int idx) {
    if (idx >= (N / 16) * 4 * 64) return;
    int l = idx & 63;
    int s = (idx >> 6) & 3;
    int c = idx >> 8;
    int n = c * 16 + (l & 15);
    int k0 = s * 32 + (l >> 4) * 8;
#pragma unroll
    for (int j = 0; j < 8; j++) {
        float w = W[(k0 + j) * N + n];
        __bf16 h = (__bf16)w;
        hi[idx * 8 + j] = h;
        lo[idx * 8 + j] = (__bf16)(w - (float)h);
    }
}

__global__ __launch_bounds__(256) void prep_kernel(
        const float* __restrict__ W1, const float* __restrict__ W2,
        __bf16* __restrict__ w1hi, __bf16* __restrict__ w1lo,
        __bf16* __restrict__ w2hi, __bf16* __restrict__ w2lo,
        int* __restrict__ gcur, __half* __restrict__ hs1, __half* __restrict__ hs2) {
    int b = blockIdx.x, tid = threadIdx.x;
    if (b < 8)       wprep_body<128>(W1, w1hi, w1lo, b * 256 + tid);
    else if (b < 12) wprep_body<64> (W2, w2hi, w2lo, (b - 8) * 256 + tid);
    else {
        for (int i = tid; i < NBIN; i += 256) gcur[i] = 0;
        if (tid < 128) hs1[(size_t)N_NODES * 128 + tid] = __float2half(0.f);
        if (tid < 64)  hs2[(size_t)N_NODES * 64 + tid] = __float2half(0.f);
    }
}

// ---------------- bin_scatter: one edge pass -> per-bin packed (dst<<16|src) -------

__global__ __launch_bounds__(256) void bin_scatter_kernel(
        const int* __restrict__ src, const int* __restrict__ dst,
        int* __restrict__ gcur, unsigned* __restrict__ ebin) {
    __shared__ int cnt[512];
    __shared__ int boff[512];
    __shared__ int bcur[512];
    __shared__ int gbase[512];
    __shared__ unsigned stage[B_CHUNK];
    __shared__ int ex[256];
    int tid = threadIdx.x;
    int e0 = blockIdx.x * B_CHUNK;

    cnt[tid] = 0; cnt[tid + 256] = 0;
    __syncthreads();

    unsigned key[8]; int bins[8];
#pragma unroll
    for (int i = 0; i < 8; i++) {
        int e = e0 + tid + i * 256;               // coalesced
        if (e < N_EDGES) {
            int d = dst[e], s = src[e];
            key[i]  = ((unsigned)d << 16) | (unsigned)s;
            bins[i] = d >> 7;
            atomicAdd(&cnt[bins[i]], 1);
        } else bins[i] = -1;
    }
    __syncthreads();

    // exclusive scan of 512 bin counts with 256 threads (2 bins each)
    int a = cnt[2 * tid], b = cnt[2 * tid + 1];
    ex[tid] = a + b;
    __syncthreads();
    for (int off = 1; off < 256; off <<= 1) {
        int t = (tid >= off) ? ex[tid - off] : 0;
        __syncthreads();
        ex[tid] += t;
        __syncthreads();
    }
    int myex = ex[tid] - (a + b);
    boff[2 * tid] = myex;     boff[2 * tid + 1] = myex + a;
    bcur[2 * tid] = myex;     bcur[2 * tid + 1] = myex + a;
    __syncthreads();

    // compact into bin-contiguous staging
#pragma unroll
    for (int i = 0; i < 8; i++) {
        if (bins[i] >= 0) {
            int p = atomicAdd(&bcur[bins[i]], 1);
            stage[p] = key[i];
        }
    }

    // bulk-reserve global bin space (one atomic per non-empty (block,bin))
    __syncthreads();
    for (int b2 = tid; b2 < NBIN; b2 += 256) {
        int c = cnt[b2];
        gbase[b2] = (c > 0) ? atomicAdd(&gcur[b2], c) : 0;
    }
    __syncthreads();

    int total = N_EDGES - e0; if (total > B_CHUNK) total = B_CHUNK;
    for (int i = tid; i < total; i += 256) {
        unsigned k = stage[i];
        int bin = (int)(k >> 23);                 // dst>>7
        int idx = gbase[bin] + (i - boff[bin]);
        if (idx < CAP) ebin[(size_t)bin * CAP + idx] = k;  // guard (11-sigma)
    }
}

// ---------------- bin_build: histogram + padded scan + sentinel fill + rank sort ---
__global__ __launch_bounds__(256) void bin_build_kernel(
        const unsigned* __restrict__ ebin, const int* __restrict__ gcur,
        int* __restrict__ deg, int* __restrict__ row_off,
        float* __restrict__ dinv, int* __restrict__ ssrc,
        int* __restrict__ perm) {
    __shared__ int dl[BINW];
    __shared__ int pref[BINW];
    __shared__ int cur[BINW];
    __shared__ int padTotal;
    int bin = blockIdx.x, tid = threadIdx.x;
    if (tid < BINW) dl[tid] = 0;
    __syncthreads();
    int cnt = gcur[bin]; if (cnt > CAP) cnt = CAP;
    const unsigned* eb = ebin + (size_t)bin * CAP;
    for (int i = tid; i < cnt; i += 256)
        atomicAdd(&dl[(eb[i] >> 16) & 127], 1);
    __syncthreads();
    // Hillis-Steele inclusive scan over 128 PADDED counts
    int pc = 0;
    if (tid < BINW) { pc = (dl[tid] + 31) & ~31; pref[tid] = pc; }
    __syncthreads();
    for (int off = 1; off < BINW; off <<= 1) {
        int t = 0;
        if (tid < BINW && tid >= off) t = pref[tid - off];
        __syncthreads();
        if (tid < BINW) pref[tid] += t;
        __syncthreads();
    }
    int node = bin * BINW + tid;
    if (tid < BINW) {
        int ex = pref[tid] - pc;                  // padded exclusive prefix
        cur[tid] = ex;
        if (node < N_NODES) {
            deg[node]     = dl[tid];
            row_off[node] = bin * CAP2 + ex;
            dinv[node]    = rsqrtf((float)(dl[tid] + 1));   // +1 self-loop
        }
        if (tid == BINW - 1) padTotal = pref[tid];
    }
    __syncthreads();
    // stable counting-rank by degree -> perm (ascending; invalid nodes last)
    if (tid < BINW) {
        int myd = (node < N_NODES) ? dl[tid] : 0x7FFFFFFF;
        int r = 0;
        for (int j = 0; j < BINW; j++) {
            int nj = bin * BINW + j;
            int dj = (nj < N_NODES) ? dl[j] : 0x7FFFFFFF;
            r += (dj < myd) || (dj == myd && j < tid);
        }
        perm[bin * BINW + r] = node;
    }
    __syncthreads();
    int pt = padTotal;
    int* sb = ssrc + (size_t)bin * CAP2;
    for (int i = tid; i < pt; i += 256) sb[i] = N_NODES;    // sentinel prefill
    __syncthreads();
    for (int i = tid; i < cnt; i += 256) {
        unsigned k = eb[i];
        int p = atomicAdd(&cur[(k >> 16) & 127], 1);
        sb[p] = (int)(k & 0xFFFFu);
    }
}

// ---------------- GEMM layer1: hs1[row][128] = fp16( dinv[row]*(X@W1)[row] ) ------
__global__ __launch_bounds__(256) void gemm_mfma128_kernel(
        const float* __restrict__ X, const __bf16* __restrict__ Whi,
        const __bf16* __restrict__ Wlo, const float* __restrict__ dinv,
        __half* __restrict__ hs) {
    constexpr int NC = 8;
    int tid = threadIdx.x;
    int w = tid >> 6, lane = tid & 63;
    int q = lane >> 4, lr = lane & 15;
    int rb = blockIdx.x * 64 + w * 16;
    int row = rb + lr;
    int rowc = (row < N_NODES) ? row : (N_NODES - 1);

    f32x4 acc[NC];
#pragma unroll
    for (int c = 0; c < NC; c++) acc[c] = (f32x4){0.f, 0.f, 0.f, 0.f};

#pragma unroll
    for (int s = 0; s < 4; s++) {
        const float* xp = X + (size_t)rowc * 128 + s * 32 + q * 8;
        float4 x0 = *(const float4*)xp;
        float4 x1 = *(const float4*)(xp + 4);
        float xv[8] = {x0.x, x0.y, x0.z, x0.w, x1.x, x1.y, x1.z, x1.w};
        bf16x8 a_hi, a_lo;
#pragma unroll
        for (int j = 0; j < 8; j++) {
            __bf16 h = (__bf16)xv[j];
            a_hi[j] = h;
            a_lo[j] = (__bf16)(xv[j] - (float)h);
        }
#pragma unroll
        for (int c = 0; c < NC; c++) {
            size_t fo = (size_t)((c * 4 + s) * 64 + lane) * 8;
            bf16x8 bh = *(const bf16x8*)(Whi + fo);
            bf16x8 bl = *(const bf16x8*)(Wlo + fo);
            acc[c] = __builtin_amdgcn_mfma_f32_16x16x32_bf16(a_hi, bh, acc[c], 0, 0, 0);
            acc[c] = __builtin_amdgcn_mfma_f32_16x16x32_bf16(a_lo, bh, acc[c], 0, 0, 0);
            acc[c] = __builtin_amdgcn_mfma_f32_16x16x32_bf16(a_hi, bl, acc[c], 0, 0, 0);
        }
    }

    // C/D layout: col = c*16 + lr, row(within 16) = q*4 + r
#pragma unroll
    for (int r = 0; r < 4; r++) {
        int grow = rb + q * 4 + r;
        if (grow < N_NODES) {
            float sc = dinv[grow];
#pragma unroll
            for (int c = 0; c < NC; c++) {
                hs[(size_t)grow * 128 + c * 16 + lr] = __float2half(acc[c][r] * sc);
            }
        }
    }
}

// ---------------- FUSED: agg128(+relu) -> LDS x2 rows -> 16x64 MFMA -> hs2 --------
// block = 1024 thr = 16 waves = 16 DEGREE-MATCHED nodes (via perm): block b
// takes ranks [group*16, group*16+16) of one bin. 390*8 + 5 = 3125 blocks.
__global__ __launch_bounds__(1024) void fused_agg_gemm_kernel(
        const __half* __restrict__ hs1, const int* __restrict__ row_off,
        const int* __restrict__ deg, const int* __restrict__ ssrc,
        const float* __restrict__ dinv, const float* __restrict__ bias,
        const __bf16* __restrict__ w2hi, const __bf16* __restrict__ w2lo,
        const int* __restrict__ perm, __half* __restrict__ hs2) {
    __shared__ float x2buf[16][132];              // pad 132: 2-way banks (free)
    __shared__ int   pnode[16];
    __shared__ float pdinv[16];
    int wave = threadIdx.x >> 6;
    int lane = threadIdx.x & 63;
    int b = blockIdx.x;
    int bin, group;
    if (b < 3120) { bin = b >> 3; group = b & 7; }
    else          { bin = 390;    group = b - 3120; }
    int node = perm[bin * BINW + group * 16 + wave];   // always < N_NODES

    int beg = row_off[node];
    int d   = deg[node];
    float di = dinv[node];
    if (lane == 0) { pnode[wave] = node; pdinv[wave] = di; }
    int hf = lane >> 5, sl = lane & 31;
    const float2* Hq = (const float2*)hs1;        // [N+1][32] 8B chunks
    float4 acc = make_float4(0.f, 0.f, 0.f, 0.f);
    for (int j = 0; j < d; j += 16) {             // padded span, sentinel-safe
        int s[8]; float2 v[8];
#pragma unroll
        for (int u = 0; u < 8; u++) s[u] = ssrc[beg + j + 2 * u + hf];
#pragma unroll
        for (int u = 0; u < 8; u++) v[u] = Hq[(size_t)s[u] * 32 + sl];
#pragma unroll
        for (int u = 0; u < 8; u++) {
            float2 f0 = __half22float2(((const __half2*)&v[u])[0]);
            float2 f1 = __half22float2(((const __half2*)&v[u])[1]);
            acc.x += f0.x; acc.y += f0.y; acc.z += f1.x; acc.w += f1.y;
        }
    }
    acc.x += __shfl_xor(acc.x, 32, 64);
    acc.y += __shfl_xor(acc.y, 32, 64);
    acc.z += __shfl_xor(acc.z, 32, 64);
    acc.w += __shfl_xor(acc.w, 32, 64);
    if (hf == 0) {
        float2 sv = Hq[(size_t)node * 32 + sl];   // self-loop
        float2 f0 = __half22float2(((const __half2*)&sv)[0]);
        float2 f1 = __half22float2(((const __half2*)&sv)[1]);
        float4 b4 = ((const float4*)bias)[sl];
        float4 o;
        o.x = fmaxf(fmaf(di, acc.x + f0.x, b4.x), 0.f);     // relu
        o.y = fmaxf(fmaf(di, acc.y + f0.y, b4.y), 0.f);
        o.z = fmaxf(fmaf(di, acc.z + f1.x, b4.z), 0.f);
        o.w = fmaxf(fmaf(di, acc.w + f1.y, b4.w), 0.f);
        *(float4*)&x2buf[wave][4 * sl] = o;
    }
    __syncthreads();

    // GEMM phase: waves 0-3, wave = col-frag c (16 cols each)
    if (threadIdx.x < 256) {
        int c = wave;
        int q = lane >> 4, lr = lane & 15;
        f32x4 g = (f32x4){0.f, 0.f, 0.f, 0.f};
#pragma unroll
        for (int s = 0; s < 4; s++) {
            const float* xp = &x2buf[lr][s * 32 + q * 8];
            float4 a0 = *(const float4*)xp;
            float4 a1 = *(const float4*)(xp + 4);
            float xv[8] = {a0.x, a0.y, a0.z, a0.w, a1.x, a1.y, a1.z, a1.w};
            bf16x8 a_hi, a_lo;
#pragma unroll
            for (int j = 0; j < 8; j++) {
                __bf16 h = (__bf16)xv[j];
                a_hi[j] = h;
                a_lo[j] = (__bf16)(xv[j] - (float)h);
            }
            size_t fo = (size_t)((c * 4 + s) * 64 + lane) * 8;
            bf16x8 bh = *(const bf16x8*)(w2hi + fo);
            bf16x8 bl = *(const bf16x8*)(w2lo + fo);
            g = __builtin_amdgcn_mfma_f32_16x16x32_bf16(a_hi, bh, g, 0, 0, 0);
            g = __builtin_amdgcn_mfma_f32_16x16x32_bf16(a_lo, bh, g, 0, 0, 0);
            g = __builtin_amdgcn_mfma_f32_16x16x32_bf16(a_hi, bl, g, 0, 0, 0);
        }
#pragma unroll
        for (int r = 0; r < 4; r++) {
            int tr = q * 4 + r;
            int grow = pnode[tr];
            hs2[(size_t)grow * 64 + c * 16 + lr] = __float2half(g[r] * pdinv[tr]);
        }
    }
}

// ---------------- Aggregate CH=64: wave/node, 8B/lane = 4 rows/instr --------------
__global__ __launch_bounds__(256) void aggregate64_kernel(
        const __half* __restrict__ hs, const int* __restrict__ row_off,
        const int* __restrict__ deg, const int* __restrict__ ssrc,
        const float* __restrict__ dinv, const float* __restrict__ bias,
        float* __restrict__ out) {
    int node = (blockIdx.x * 256 + threadIdx.x) >> 6;
    int lane = threadIdx.x & 63;
    if (node >= N_NODES) return;
    int beg = row_off[node];
    int d   = deg[node];
    float di = dinv[node];
    int qt = lane >> 4, sl = lane & 15;
    const float2* Hq = (const float2*)hs;        // [N+1][16] 8B chunks
    float4 acc = make_float4(0.f, 0.f, 0.f, 0.f);
    for (int j = 0; j < d; j += 32) {            // padded span, sentinel-safe
        int s[8]; float2 v[8];
#pragma unroll
        for (int u = 0; u < 8; u++) s[u] = ssrc[beg + j + 4 * u + qt];
#pragma unroll
        for (int u = 0; u < 8; u++) v[u] = Hq[(size_t)s[u] * 16 + sl];
#pragma unroll
        for (int u = 0; u < 8; u++) {
            float2 f0 = __half22float2(((const __half2*)&v[u])[0]);
            float2 f1 = __half22float2(((const __half2*)&v[u])[1]);
            acc.x += f0.x; acc.y += f0.y; acc.z += f1.x; acc.w += f1.y;
        }
    }
    acc.x += __shfl_xor(acc.x, 16, 64);
    acc.y += __shfl_xor(acc.y, 16, 64);
    acc.z += __shfl_xor(acc.z, 16, 64);
    acc.w += __shfl_xor(acc.w, 16, 64);
    acc.x += __shfl_xor(acc.x, 32, 64);
    acc.y += __shfl_xor(acc.y, 32, 64);
    acc.z += __shfl_xor(acc.z, 32, 64);
    acc.w += __shfl_xor(acc.w, 32, 64);
    if (lane < 16) {
        float2 sv = Hq[(size_t)node * 16 + sl];  // self-loop
        float2 f0 = __half22float2(((const __half2*)&sv)[0]);
        float2 f1 = __half22float2(((const __half2*)&sv)[1]);
        float4 b = ((const float4*)bias)[sl];
        float4 o;
        o.x = fmaf(di, acc.x + f0.x, b.x);
        o.y = fmaf(di, acc.y + f0.y, b.y);
        o.z = fmaf(di, acc.z + f1.x, b.z);
        o.w = fmaf(di, acc.w + f1.y, b.w);
        ((float4*)out)[(size_t)node * 16 + sl] = o;
    }
}

// ---------------- launch ----------------

extern "C" void kernel_launch(void* const* d_in, const int* in_sizes, int n_in,
                              void* d_out, int out_size, void* d_ws, size_t ws_size,
                              hipStream_t stream) {
    const float* x  = (const float*)d_in[0];   // [N,128]
    const int*   ei = (const int*)d_in[1];     // [2,E]
    const float* W1 = (const float*)d_in[2];   // [128,128]
    const float* b1 = (const float*)d_in[3];   // [128]
    const float* W2 = (const float*)d_in[4];   // [128,64]
    const float* b2 = (const float*)d_in[5];   // [64]
    float* out = (float*)d_out;                // [N,64]

    const int* src = ei;
    const int* dst = ei + N_EDGES;

    char* p = (char*)d_ws;
    size_t off = 0;
    auto alloc = [&](size_t bytes) { void* q = p + off; off += (bytes + 255) & ~(size_t)255; return q; };
    float*    dinv    = (float*)   alloc(N_NODES * 4);
    int*      deg     = (int*)     alloc(N_NODES * 4);
    int*      row_off = (int*)     alloc(N_NODES * 4);
    int*      gcur    = (int*)     alloc(NBIN * 4);
    int*      perm    = (int*)     alloc(NBIN * BINW * 4);          // 200 KB
    int*      ssrc    = (int*)     alloc((size_t)NBIN * CAP2 * 4);  // 10.4 MB
    unsigned* ebin    = (unsigned*)alloc((size_t)NBIN * CAP * 4);   // 4.0 MB
    __bf16*   w1hi    = (__bf16*)  alloc(128 * 128 * 2);
    __bf16*   w1lo    = (__bf16*)  alloc(128 * 128 * 2);
    __bf16*   w2hi    = (__bf16*)  alloc(128 * 64 * 2);
    __bf16*   w2lo    = (__bf16*)  alloc(128 * 64 * 2);
    __half*   hs1     = (__half*)  alloc((size_t)(N_NODES + 1) * 128 * 2);
    __half*   hs2     = (__half*)  alloc((size_t)(N_NODES + 1) * 64 * 2);

    // 6 launches total
    prep_kernel<<<13, 256, 0, stream>>>(W1, W2, w1hi, w1lo, w2hi, w2lo, gcur, hs1, hs2);
    bin_scatter_kernel<<<NB_SCAT, 256, 0, stream>>>(src, dst, gcur, ebin);
    bin_build_kernel<<<NBIN, 256, 0, stream>>>(ebin, gcur, deg, row_off, dinv, ssrc, perm);

    gemm_mfma128_kernel<<<(N_NODES + 63) / 64, 256, 0, stream>>>(x, w1hi, w1lo, dinv, hs1);
    fused_agg_gemm_kernel<<<3125, 1024, 0, stream>>>(
        hs1, row_off, deg, ssrc, dinv, b1, w2hi, w2lo, perm, hs2);
    aggregate64_kernel<<<(N_NODES * 64 + 255) / 256, 256, 0, stream>>>(
        hs2, row_off, deg, ssrc, dinv, b2, out);
}

// Round 14
// 185.243 us; speedup vs baseline: 1.0539x; 1.0539x over previous
//
#include <hip/hip_runtime.h>
#include <hip/hip_fp16.h>

// GCN 2-layer: N=50000 nodes, E=800000 edges, 128 -> 128(relu) -> 64
// R14: revert R13's degree-perm (regressed: grid-level skew > within-block
// Poisson variance). Back to R12 structure + sentinel prefill moved from
// bin_build to prep (bulk parallel int4 fill, removes a barrier + 13MB of
// writes from the 391-block build).
// Evidence log: R2 MLP depth win; R4/R9 sliced layouts dead; flat gather
// 86.6MB compulsory at ~2.2TB/s random-line ceiling; R11 sentinel pad win;
// R12 fusion ~neutral but -1 launch; R13 perm regression (reverted).

#define N_NODES 50000
#define N_EDGES 800000
#define BINW    128
#define NBIN    391                    // ceil(50000/128)
#define CAP     2560                   // mean bin load 2046, ~11 sigma margin
#define CAP2    6656                   // padded: up to 2560 + 128*31
#define B_CHUNK 2048
#define NB_SCAT ((N_EDGES + B_CHUNK - 1) / B_CHUNK)   // 391

typedef __bf16 bf16x8 __attribute__((ext_vector_type(8)));
typedef float  f32x4  __attribute__((ext_vector_type(4)));

// ---------------- prep: W-frags, gcur zero, sentinel rows, ssrc sentinel fill ------
template<int N>
__device__ inline void wprep_body(const float* __restrict__ W,
                                  __bf16* __restrict__ hi, __bf16* __restrict__ lo,
                                  int idx) {
    if (idx >= (N / 16) * 4 * 64) return;
    int l = idx & 63;
    int s = (idx >> 6) & 3;
    int c = idx >> 8;
    int n = c * 16 + (l & 15);
    int k0 = s * 32 + (l >> 4) * 8;
#pragma unroll
    for (int j = 0; j < 8; j++) {
        float w = W[(k0 + j) * N + n];
        __bf16 h = (__bf16)w;
        hi[idx * 8 + j] = h;
        lo[idx * 8 + j] = (__bf16)(w - (float)h);
    }
}

__global__ __launch_bounds__(256) void prep_kernel(
        const float* __restrict__ W1, const float* __restrict__ W2,
        __bf16* __restrict__ w1hi, __bf16* __restrict__ w1lo,
        __bf16* __restrict__ w2hi, __bf16* __restrict__ w2lo,
        int* __restrict__ gcur, __half* __restrict__ hs1, __half* __restrict__ hs2,
        int* __restrict__ ssrc) {
    int b = blockIdx.x, tid = threadIdx.x;
    if (b < 8)       wprep_body<128>(W1, w1hi, w1lo, b * 256 + tid);
    else if (b < 12) wprep_body<64> (W2, w2hi, w2lo, (b - 8) * 256 + tid);
    else if (b == 12) {
        for (int i = tid; i < NBIN; i += 256) gcur[i] = 0;
        if (tid < 128) hs1[(size_t)N_NODES * 128 + tid] = __float2half(0.f);
        if (tid < 64)  hs2[(size_t)N_NODES * 64 + tid] = __float2half(0.f);
    } else {
        // blocks 13..76: bulk sentinel fill of ssrc (int4 stores)
        const int total4 = (NBIN * CAP2) / 4;     // 650,624 int4s
        int4 sv = make_int4(N_NODES, N_NODES, N_NODES, N_NODES);
        int4* p4 = (int4*)ssrc;
        for (int i = (b - 13) * 256 + tid; i < total4; i += 64 * 256) p4[i] = sv;
    }
}

// ---------------- bin_scatter: one edge pass -> per-bin packed (dst<<16|src) -------

__global__ __launch_bounds__(256) void bin_scatter_kernel(
        const int* __restrict__ src, const int* __restrict__ dst,
        int* __restrict__ gcur, unsigned* __restrict__ ebin) {
    __shared__ int cnt[512];
    __shared__ int boff[512];
    __shared__ int bcur[512];
    __shared__ int gbase[512];
    __shared__ unsigned stage[B_CHUNK];
    __shared__ int ex[256];
    int tid = threadIdx.x;
    int e0 = blockIdx.x * B_CHUNK;

    cnt[tid] = 0; cnt[tid + 256] = 0;
    __syncthreads();

    unsigned key[8]; int bins[8];
#pragma unroll
    for (int i = 0; i < 8; i++) {
        int e = e0 + tid + i * 256;               // coalesced
        if (e < N_EDGES) {
            int d = dst[e], s = src[e];
            key[i]  = ((unsigned)d << 16) | (unsigned)s;
            bins[i] = d >> 7;
            atomicAdd(&cnt[bins[i]], 1);
        } else bins[i] = -1;
    }
    __syncthreads();

    // exclusive scan of 512 bin counts with 256 threads (2 bins each)
    int a = cnt[2 * tid], b = cnt[2 * tid + 1];
    ex[tid] = a + b;
    __syncthreads();
    for (int off = 1; off < 256; off <<= 1) {
        int t = (tid >= off) ? ex[tid - off] : 0;
        __syncthreads();
        ex[tid] += t;
        __syncthreads();
    }
    int myex = ex[tid] - (a + b);
    boff[2 * tid] = myex;     boff[2 * tid + 1] = myex + a;
    bcur[2 * tid] = myex;     bcur[2 * tid + 1] = myex + a;
    __syncthreads();

    // compact into bin-contiguous staging
#pragma unroll
    for (int i = 0; i < 8; i++) {
        if (bins[i] >= 0) {
            int p = atomicAdd(&bcur[bins[i]], 1);
            stage[p] = key[i];
        }
    }

    // bulk-reserve global bin space (one atomic per non-empty (block,bin))
    __syncthreads();
    for (int b2 = tid; b2 < NBIN; b2 += 256) {
        int c = cnt[b2];
        gbase[b2] = (c > 0) ? atomicAdd(&gcur[b2], c) : 0;
    }
    __syncthreads();

    int total = N_EDGES - e0; if (total > B_CHUNK) total = B_CHUNK;
    for (int i = tid; i < total; i += 256) {
        unsigned k = stage[i];
        int bin = (int)(k >> 23);                 // dst>>7
        int idx = gbase[bin] + (i - boff[bin]);
        if (idx < CAP) ebin[(size_t)bin * CAP + idx] = k;  // guard (11-sigma)
    }
}

// ---------------- bin_build: histogram + padded scan + fill (sentinels pre-laid) ---
__global__ __launch_bounds__(256) void bin_build_kernel(
        const unsigned* __restrict__ ebin, const int* __restrict__ gcur,
        int* __restrict__ deg, int* __restrict__ row_off,
        float* __restrict__ dinv, int* __restrict__ ssrc) {
    __shared__ int dl[BINW];
    __shared__ int pref[BINW];
    __shared__ int cur[BINW];
    int bin = blockIdx.x, tid = threadIdx.x;
    if (tid < BINW) dl[tid] = 0;
    __syncthreads();
    int cnt = gcur[bin]; if (cnt > CAP) cnt = CAP;
    const unsigned* eb = ebin + (size_t)bin * CAP;
    for (int i = tid; i < cnt; i += 256)
        atomicAdd(&dl[(eb[i] >> 16) & 127], 1);
    __syncthreads();
    // Hillis-Steele inclusive scan over 128 PADDED counts
    int pc = 0;
    if (tid < BINW) { pc = (dl[tid] + 31) & ~31; pref[tid] = pc; }
    __syncthreads();
    for (int off = 1; off < BINW; off <<= 1) {
        int t = 0;
        if (tid < BINW && tid >= off) t = pref[tid - off];
        __syncthreads();
        if (tid < BINW) pref[tid] += t;
        __syncthreads();
    }
    if (tid < BINW) {
        int ex = pref[tid] - pc;                  // padded exclusive prefix
        cur[tid] = ex;
        int node = bin * BINW + tid;
        if (node < N_NODES) {
            deg[node]     = dl[tid];
            row_off[node] = bin * CAP2 + ex;
            dinv[node]    = rsqrtf((float)(dl[tid] + 1));   // +1 self-loop
        }
    }
    __syncthreads();
    int* sb = ssrc + (size_t)bin * CAP2;          // pads already = N_NODES (prep)
    for (int i = tid; i < cnt; i += 256) {
        unsigned k = eb[i];
        int p = atomicAdd(&cur[(k >> 16) & 127], 1);
        sb[p] = (int)(k & 0xFFFFu);
    }
}

// ---------------- GEMM layer1: hs1[row][128] = fp16( dinv[row]*(X@W1)[row] ) ------
__global__ __launch_bounds__(256) void gemm_mfma128_kernel(
        const float* __restrict__ X, const __bf16* __restrict__ Whi,
        const __bf16* __restrict__ Wlo, const float* __restrict__ dinv,
        __half* __restrict__ hs) {
    constexpr int NC = 8;
    int tid = threadIdx.x;
    int w = tid >> 6, lane = tid & 63;
    int q = lane >> 4, lr = lane & 15;
    int rb = blockIdx.x * 64 + w * 16;
    int row = rb + lr;
    int rowc = (row < N_NODES) ? row : (N_NODES - 1);

    f32x4 acc[NC];
#pragma unroll
    for (int c = 0; c < NC; c++) acc[c] = (f32x4){0.f, 0.f, 0.f, 0.f};

#pragma unroll
    for (int s = 0; s < 4; s++) {
        const float* xp = X + (size_t)rowc * 128 + s * 32 + q * 8;
        float4 x0 = *(const float4*)xp;
        float4 x1 = *(const float4*)(xp + 4);
        float xv[8] = {x0.x, x0.y, x0.z, x0.w, x1.x, x1.y, x1.z, x1.w};
        bf16x8 a_hi, a_lo;
#pragma unroll
        for (int j = 0; j < 8; j++) {
            __bf16 h = (__bf16)xv[j];
            a_hi[j] = h;
            a_lo[j] = (__bf16)(xv[j] - (float)h);
        }
#pragma unroll
        for (int c = 0; c < NC; c++) {
            size_t fo = (size_t)((c * 4 + s) * 64 + lane) * 8;
            bf16x8 bh = *(const bf16x8*)(Whi + fo);
            bf16x8 bl = *(const bf16x8*)(Wlo + fo);
            acc[c] = __builtin_amdgcn_mfma_f32_16x16x32_bf16(a_hi, bh, acc[c], 0, 0, 0);
            acc[c] = __builtin_amdgcn_mfma_f32_16x16x32_bf16(a_lo, bh, acc[c], 0, 0, 0);
            acc[c] = __builtin_amdgcn_mfma_f32_16x16x32_bf16(a_hi, bl, acc[c], 0, 0, 0);
        }
    }

    // C/D layout: col = c*16 + lr, row(within 16) = q*4 + r
#pragma unroll
    for (int r = 0; r < 4; r++) {
        int grow = rb + q * 4 + r;
        if (grow < N_NODES) {
            float sc = dinv[grow];
#pragma unroll
            for (int c = 0; c < NC; c++) {
                hs[(size_t)grow * 128 + c * 16 + lr] = __float2half(acc[c][r] * sc);
            }
        }
    }
}

// ---------------- FUSED: agg128(+relu) -> LDS x2 rows -> 16x64 MFMA -> hs2 --------
// block = 1024 thr = 16 waves = 16 consecutive nodes (50000 = 3125*16 exact).
__global__ __launch_bounds__(1024) void fused_agg_gemm_kernel(
        const __half* __restrict__ hs1, const int* __restrict__ row_off,
        const int* __restrict__ deg, const int* __restrict__ ssrc,
        const float* __restrict__ dinv, const float* __restrict__ bias,
        const __bf16* __restrict__ w2hi, const __bf16* __restrict__ w2lo,
        __half* __restrict__ hs2) {
    __shared__ float x2buf[16][132];              // pad 132: 2-way banks (free)
    int wave = threadIdx.x >> 6;
    int lane = threadIdx.x & 63;
    int rb = blockIdx.x * 16;
    int node = rb + wave;                         // always < N_NODES

    int beg = row_off[node];
    int d   = deg[node];
    float di = dinv[node];
    int hf = lane >> 5, sl = lane & 31;
    const float2* Hq = (const float2*)hs1;        // [N+1][32] 8B chunks
    float4 acc = make_float4(0.f, 0.f, 0.f, 0.f);
    for (int j = 0; j < d; j += 16) {             // padded span, sentinel-safe
        int s[8]; float2 v[8];
#pragma unroll
        for (int u = 0; u < 8; u++) s[u] = ssrc[beg + j + 2 * u + hf];
#pragma unroll
        for (int u = 0; u < 8; u++) v[u] = Hq[(size_t)s[u] * 32 + sl];
#pragma unroll
        for (int u = 0; u < 8; u++) {
            float2 f0 = __half22float2(((const __half2*)&v[u])[0]);
            float2 f1 = __half22float2(((const __half2*)&v[u])[1]);
            acc.x += f0.x; acc.y += f0.y; acc.z += f1.x; acc.w += f1.y;
        }
    }
    acc.x += __shfl_xor(acc.x, 32, 64);
    acc.y += __shfl_xor(acc.y, 32, 64);
    acc.z += __shfl_xor(acc.z, 32, 64);
    acc.w += __shfl_xor(acc.w, 32, 64);
    if (hf == 0) {
        float2 sv = Hq[(size_t)node * 32 + sl];   // self-loop
        float2 f0 = __half22float2(((const __half2*)&sv)[0]);
        float2 f1 = __half22float2(((const __half2*)&sv)[1]);
        float4 b4 = ((const float4*)bias)[sl];
        float4 o;
        o.x = fmaxf(fmaf(di, acc.x + f0.x, b4.x), 0.f);     // relu
        o.y = fmaxf(fmaf(di, acc.y + f0.y, b4.y), 0.f);
        o.z = fmaxf(fmaf(di, acc.z + f1.x, b4.z), 0.f);
        o.w = fmaxf(fmaf(di, acc.w + f1.y, b4.w), 0.f);
        *(float4*)&x2buf[wave][4 * sl] = o;
    }
    __syncthreads();

    // GEMM phase: waves 0-3, wave = col-frag c (16 cols each)
    if (threadIdx.x < 256) {
        int c = wave;
        int q = lane >> 4, lr = lane & 15;
        f32x4 g = (f32x4){0.f, 0.f, 0.f, 0.f};
#pragma unroll
        for (int s = 0; s < 4; s++) {
            const float* xp = &x2buf[lr][s * 32 + q * 8];
            float4 a0 = *(const float4*)xp;
            float4 a1 = *(const float4*)(xp + 4);
            float xv[8] = {a0.x, a0.y, a0.z, a0.w, a1.x, a1.y, a1.z, a1.w};
            bf16x8 a_hi, a_lo;
#pragma unroll
            for (int j = 0; j < 8; j++) {
                __bf16 h = (__bf16)xv[j];
                a_hi[j] = h;
                a_lo[j] = (__bf16)(xv[j] - (float)h);
            }
            size_t fo = (size_t)((c * 4 + s) * 64 + lane) * 8;
            bf16x8 bh = *(const bf16x8*)(w2hi + fo);
            bf16x8 bl = *(const bf16x8*)(w2lo + fo);
            g = __builtin_amdgcn_mfma_f32_16x16x32_bf16(a_hi, bh, g, 0, 0, 0);
            g = __builtin_amdgcn_mfma_f32_16x16x32_bf16(a_lo, bh, g, 0, 0, 0);
            g = __builtin_amdgcn_mfma_f32_16x16x32_bf16(a_hi, bl, g, 0, 0, 0);
        }
#pragma unroll
        for (int r = 0; r < 4; r++) {
            int grow = rb + q * 4 + r;
            hs2[(size_t)grow * 64 + c * 16 + lr] = __float2half(g[r] * dinv[grow]);
        }
    }
}

// ---------------- Aggregate CH=64: wave/node, 8B/lane = 4 rows/instr --------------
__global__ __launch_bounds__(256) void aggregate64_kernel(
        const __half* __restrict__ hs, const int* __restrict__ row_off,
        const int* __restrict__ deg, const int* __restrict__ ssrc,
        const float* __restrict__ dinv, const float* __restrict__ bias,
        float* __restrict__ out) {
    int node = (blockIdx.x * 256 + threadIdx.x) >> 6;
    int lane = threadIdx.x & 63;
    if (node >= N_NODES) return;
    int beg = row_off[node];
    int d   = deg[node];
    float di = dinv[node];
    int qt = lane >> 4, sl = lane & 15;
    const float2* Hq = (const float2*)hs;        // [N+1][16] 8B chunks
    float4 acc = make_float4(0.f, 0.f, 0.f, 0.f);
    for (int j = 0; j < d; j += 32) {            // padded span, sentinel-safe
        int s[8]; float2 v[8];
#pragma unroll
        for (int u = 0; u < 8; u++) s[u] = ssrc[beg + j + 4 * u + qt];
#pragma unroll
        for (int u = 0; u < 8; u++) v[u] = Hq[(size_t)s[u] * 16 + sl];
#pragma unroll
        for (int u = 0; u < 8; u++) {
            float2 f0 = __half22float2(((const __half2*)&v[u])[0]);
            float2 f1 = __half22float2(((const __half2*)&v[u])[1]);
            acc.x += f0.x; acc.y += f0.y; acc.z += f1.x; acc.w += f1.y;
        }
    }
    acc.x += __shfl_xor(acc.x, 16, 64);
    acc.y += __shfl_xor(acc.y, 16, 64);
    acc.z += __shfl_xor(acc.z, 16, 64);
    acc.w += __shfl_xor(acc.w, 16, 64);
    acc.x += __shfl_xor(acc.x, 32, 64);
    acc.y += __shfl_xor(acc.y, 32, 64);
    acc.z += __shfl_xor(acc.z, 32, 64);
    acc.w += __shfl_xor(acc.w, 32, 64);
    if (lane < 16) {
        float2 sv = Hq[(size_t)node * 16 + sl];  // self-loop
        float2 f0 = __half22float2(((const __half2*)&sv)[0]);
        float2 f1 = __half22float2(((const __half2*)&sv)[1]);
        float4 b = ((const float4*)bias)[sl];
        float4 o;
        o.x = fmaf(di, acc.x + f0.x, b.x);
        o.y = fmaf(di, acc.y + f0.y, b.y);
        o.z = fmaf(di, acc.z + f1.x, b.z);
        o.w = fmaf(di, acc.w + f1.y, b.w);
        ((float4*)out)[(size_t)node * 16 + sl] = o;
    }
}

// ---------------- launch ----------------

extern "C" void kernel_launch(void* const* d_in, const int* in_sizes, int n_in,
                              void* d_out, int out_size, void* d_ws, size_t ws_size,
                              hipStream_t stream) {
    const float* x  = (const float*)d_in[0];   // [N,128]
    const int*   ei = (const int*)d_in[1];     // [2,E]
    const float* W1 = (const float*)d_in[2];   // [128,128]
    const float* b1 = (const float*)d_in[3];   // [128]
    const float* W2 = (const float*)d_in[4];   // [128,64]
    const float* b2 = (const float*)d_in[5];   // [64]
    float* out = (float*)d_out;                // [N,64]

    const int* src = ei;
    const int* dst = ei + N_EDGES;

    char* p = (char*)d_ws;
    size_t off = 0;
    auto alloc = [&](size_t bytes) { void* q = p + off; off += (bytes + 255) & ~(size_t)255; return q; };
    float*    dinv    = (float*)   alloc(N_NODES * 4);
    int*      deg     = (int*)     alloc(N_NODES * 4);
    int*      row_off = (int*)     alloc(N_NODES * 4);
    int*      gcur    = (int*)     alloc(NBIN * 4);
    int*      ssrc    = (int*)     alloc((size_t)NBIN * CAP2 * 4);  // 10.4 MB
    unsigned* ebin    = (unsigned*)alloc((size_t)NBIN * CAP * 4);   // 4.0 MB
    __bf16*   w1hi    = (__bf16*)  alloc(128 * 128 * 2);
    __bf16*   w1lo    = (__bf16*)  alloc(128 * 128 * 2);
    __bf16*   w2hi    = (__bf16*)  alloc(128 * 64 * 2);
    __bf16*   w2lo    = (__bf16*)  alloc(128 * 64 * 2);
    __half*   hs1     = (__half*)  alloc((size_t)(N_NODES + 1) * 128 * 2);
    __half*   hs2     = (__half*)  alloc((size_t)(N_NODES + 1) * 64 * 2);

    // 6 launches total
    prep_kernel<<<77, 256, 0, stream>>>(W1, W2, w1hi, w1lo, w2hi, w2lo, gcur,
                                        hs1, hs2, ssrc);
    bin_scatter_kernel<<<NB_SCAT, 256, 0, stream>>>(src, dst, gcur, ebin);
    bin_build_kernel<<<NBIN, 256, 0, stream>>>(ebin, gcur, deg, row_off, dinv, ssrc);

    gemm_mfma128_kernel<<<(N_NODES + 63) / 64, 256, 0, stream>>>(x, w1hi, w1lo, dinv, hs1);
    fused_agg_gemm_kernel<<<N_NODES / 16, 1024, 0, stream>>>(
        hs1, row_off, deg, ssrc, dinv, b1, w2hi, w2lo, hs2);
    aggregate64_kernel<<<(N_NODES * 64 + 255) / 256, 256, 0, stream>>>(
        hs2, row_off, deg, ssrc, dinv, b2, out);
}